// Round 2
// baseline (327.163 us; speedup 1.0000x reference)
//
#include <hip/hip_runtime.h>
#include <math.h>

#define NN 100000
#define NE 1600000
#define FIN 50
#define NC 16
#define SCAN_BS 1024
#define NB_SCAN ((NN + SCAN_BS - 1) / SCAN_BS)   // 98

// ---------------------------------------------------------------------------
// Kernel 1: y_l = x @ W_l^T (to ws), self = x @ W_r^T (to d_out "out" half)
// ---------------------------------------------------------------------------
__global__ __launch_bounds__(256) void lin_kernel(
    const float* __restrict__ x,
    const float* __restrict__ W_l,
    const float* __restrict__ W_r,
    float* __restrict__ y_l,
    float* __restrict__ self_out)
{
    __shared__ float sWl[NC * FIN];
    __shared__ float sWr[NC * FIN];
    __shared__ float sx[16 * FIN];

    const int tid = threadIdx.x;
    for (int i = tid; i < NC * FIN; i += 256) {
        sWl[i] = W_l[i];
        sWr[i] = W_r[i];
    }
    const int node0 = blockIdx.x * 16;
    for (int i = tid; i < 16 * FIN; i += 256) {
        int n = node0 + i / FIN;
        sx[i] = (n < NN) ? x[n * FIN + (i % FIN)] : 0.0f;
    }
    __syncthreads();

    const int ln = tid >> 4;
    const int c  = tid & 15;
    const int n  = node0 + ln;
    if (n >= NN) return;

    float accl = 0.0f, accr = 0.0f;
    const float* xr  = &sx[ln * FIN];
    const float* wlr = &sWl[c * FIN];
    const float* wrr = &sWr[c * FIN];
#pragma unroll
    for (int k = 0; k < FIN; ++k) {
        float xv = xr[k];
        accl = fmaf(xv, wlr[k], accl);
        accr = fmaf(xv, wrr[k], accr);
    }
    y_l[n * NC + c]      = accl;
    self_out[n * NC + c] = accr;
}

// ---------------------------------------------------------------------------
// Kernel 2: histogram of targets (int atomics, 1.6M)
// ---------------------------------------------------------------------------
__global__ __launch_bounds__(256) void hist_kernel(
    const int* __restrict__ ei, int* __restrict__ P)
{
    int e = blockIdx.x * 256 + threadIdx.x;
    if (e < NE) atomicAdd(&P[ei[NE + e]], 1);
}

// ---------------------------------------------------------------------------
// Kernels 3a/3b/3c: exclusive scan of P[0..NN) in place (3-pass)
// ---------------------------------------------------------------------------
__global__ __launch_bounds__(SCAN_BS) void scan1_kernel(
    int* __restrict__ P, int* __restrict__ S)
{
    __shared__ int buf[SCAN_BS];
    int i = blockIdx.x * SCAN_BS + threadIdx.x;
    int v = (i < NN) ? P[i] : 0;
    buf[threadIdx.x] = v;
    __syncthreads();
    for (int off = 1; off < SCAN_BS; off <<= 1) {
        int t = (threadIdx.x >= off) ? buf[threadIdx.x - off] : 0;
        __syncthreads();
        buf[threadIdx.x] += t;
        __syncthreads();
    }
    if (i < NN) P[i] = buf[threadIdx.x] - v;               // exclusive within block
    if (threadIdx.x == SCAN_BS - 1) S[blockIdx.x] = buf[threadIdx.x];
}

__global__ void scan2_kernel(int* __restrict__ S)
{
    if (threadIdx.x == 0) {
        int acc = 0;
        for (int b = 0; b < NB_SCAN; ++b) { int v = S[b]; S[b] = acc; acc += v; }
    }
}

__global__ __launch_bounds__(SCAN_BS) void scan3_kernel(
    int* __restrict__ P, const int* __restrict__ S)
{
    int i = blockIdx.x * SCAN_BS + threadIdx.x;
    if (i < NN) P[i] += S[blockIdx.x];
}

// ---------------------------------------------------------------------------
// Kernel 4: place src ids into target-sorted order.
// pos = atomicAdd(&P[t],1): after this kernel P[n] = end of segment n,
// and start of segment n = (n==0) ? 0 : P[n-1].
// ---------------------------------------------------------------------------
__global__ __launch_bounds__(256) void place_kernel(
    const int* __restrict__ ei, int* __restrict__ P, int* __restrict__ ssrc)
{
    int e = blockIdx.x * 256 + threadIdx.x;
    if (e >= NE) return;
    int s = ei[e];
    int t = ei[NE + e];
    int pos = atomicAdd(&P[t], 1);
    ssrc[pos] = s;
}

// ---------------------------------------------------------------------------
// Kernel 5: contention-free segment reduce + mean + bias + self + log_softmax
// 16 lanes per node.
// ---------------------------------------------------------------------------
__global__ __launch_bounds__(256) void segfin_kernel(
    const int* __restrict__ P, const int* __restrict__ ssrc,
    const float* __restrict__ y_l, const float* __restrict__ b_l,
    float* __restrict__ logp, float* __restrict__ outv)
{
    int tid = blockIdx.x * 256 + threadIdx.x;
    int n = tid >> 4;
    int c = tid & 15;
    if (n >= NN) return;

    int end   = P[n];
    int start = (n == 0) ? 0 : P[n - 1];

    float acc = 0.0f;
    int i = start;
    for (; i + 4 <= end; i += 4) {
        int s0 = ssrc[i], s1 = ssrc[i + 1], s2 = ssrc[i + 2], s3 = ssrc[i + 3];
        float a0 = y_l[s0 * NC + c];
        float a1 = y_l[s1 * NC + c];
        float a2 = y_l[s2 * NC + c];
        float a3 = y_l[s3 * NC + c];
        acc += (a0 + a1) + (a2 + a3);
    }
    for (; i < end; ++i) acc += y_l[ssrc[i] * NC + c];

    float d = fmaxf((float)(end - start), 1.0f);
    float val = acc / d + b_l[c] + outv[n * NC + c];

    float m = val;
#pragma unroll
    for (int off = 1; off < 16; off <<= 1)
        m = fmaxf(m, __shfl_xor(m, off, 16));
    float ex = expf(val - m);
    float ss = ex;
#pragma unroll
    for (int off = 1; off < 16; off <<= 1)
        ss += __shfl_xor(ss, off, 16);

    logp[n * NC + c] = val - m - logf(ss);
    outv[n * NC + c] = val;
}

extern "C" void kernel_launch(void* const* d_in, const int* in_sizes, int n_in,
                              void* d_out, int out_size, void* d_ws, size_t ws_size,
                              hipStream_t stream) {
    const float* x   = (const float*)d_in[0];
    const int*   ei  = (const int*)d_in[1];
    const float* W_l = (const float*)d_in[2];
    const float* b_l = (const float*)d_in[3];
    const float* W_r = (const float*)d_in[4];

    float* logp = (float*)d_out;
    float* outv = (float*)d_out + (size_t)NN * NC;

    // ws layout: y_l [NN*NC f32] | P [NN i32] | S [128 i32] | ssrc [NE i32]
    float* y_l  = (float*)d_ws;
    int*   P    = (int*)(y_l + (size_t)NN * NC);
    int*   S    = P + NN;
    int*   ssrc = S + 128;

    hipMemsetAsync(P, 0, NN * sizeof(int), stream);

    lin_kernel<<<(NN + 15) / 16, 256, 0, stream>>>(x, W_l, W_r, y_l, outv);
    hist_kernel<<<(NE + 255) / 256, 256, 0, stream>>>(ei, P);
    scan1_kernel<<<NB_SCAN, SCAN_BS, 0, stream>>>(P, S);
    scan2_kernel<<<1, 64, 0, stream>>>(S);
    scan3_kernel<<<NB_SCAN, SCAN_BS, 0, stream>>>(P, S);
    place_kernel<<<(NE + 255) / 256, 256, 0, stream>>>(ei, P, ssrc);
    segfin_kernel<<<(NN * NC + 255) / 256, 256, 0, stream>>>(P, ssrc, y_l, b_l, logp, outv);
}

// Round 3
// 248.918 us; speedup vs baseline: 1.3143x; 1.3143x over previous
//
#include <hip/hip_runtime.h>
#include <hip/hip_fp16.h>
#include <math.h>

#define NN 100000
#define NE 1600000
#define FIN 50
#define NC 16
#define TILE_NODES 32

// ---------------------------------------------------------------------------
// Kernel 1: y_l = x @ W_l^T (f16, to ws), self = x @ W_r^T (f32, to d_out).
// W staged in LDS once per block; grid-stride over 32-node tiles.
// Thread layout: ln = tid>>3 (node 0..31), cp = tid&7 (class pair 0..7).
// ---------------------------------------------------------------------------
__global__ __launch_bounds__(256) void lin_kernel(
    const float* __restrict__ x,
    const float* __restrict__ W_l,
    const float* __restrict__ W_r,
    __half2* __restrict__ y_l,        // [NN*8]
    float* __restrict__ self_out)     // [NN*NC] f32
{
    __shared__ float sWl[NC * FIN];
    __shared__ float sWr[NC * FIN];
    __shared__ float sx[TILE_NODES * FIN];

    const int tid = threadIdx.x;
    for (int i = tid; i < NC * FIN; i += 256) {
        sWl[i] = W_l[i];
        sWr[i] = W_r[i];
    }

    const int ntiles = (NN + TILE_NODES - 1) / TILE_NODES;
    const int ln = tid >> 3;
    const int cp = tid & 7;

    for (int tile = blockIdx.x; tile < ntiles; tile += gridDim.x) {
        __syncthreads();   // guards W fill (first iter) and sx reuse (later iters)
        const int node0 = tile * TILE_NODES;
        for (int i = tid; i < TILE_NODES * FIN; i += 256) {
            int n = node0 + i / FIN;
            sx[i] = (n < NN) ? x[n * FIN + (i % FIN)] : 0.0f;
        }
        __syncthreads();

        const int n = node0 + ln;
        if (n >= NN) continue;

        const float* xr = &sx[ln * FIN];
        const float* w0 = &sWl[(2 * cp) * FIN];
        const float* w1 = w0 + FIN;
        const float* u0 = &sWr[(2 * cp) * FIN];
        const float* u1 = u0 + FIN;

        float a0 = 0.f, a1 = 0.f, r0 = 0.f, r1 = 0.f;
#pragma unroll
        for (int k = 0; k < FIN; ++k) {
            float xv = xr[k];
            a0 = fmaf(xv, w0[k], a0);
            a1 = fmaf(xv, w1[k], a1);
            r0 = fmaf(xv, u0[k], r0);
            r1 = fmaf(xv, u1[k], r1);
        }
        y_l[n * 8 + cp] = __floats2half2_rn(a0, a1);
        ((float2*)self_out)[n * 8 + cp] = make_float2(r0, r1);
    }
}

// ---------------------------------------------------------------------------
// Kernel 2: edge scatter with packed-f16 hardware atomics.
// 8 lanes per edge: lane cp adds y_l[s*8+cp] (2 classes) into agg[t*8+cp];
// lane 0 bumps deg[t]. 9 atomic dwords/edge vs 17 in the fp32 version.
// ---------------------------------------------------------------------------
__global__ __launch_bounds__(256) void scatter_kernel(
    const int* __restrict__ ei,       // [2, NE]
    const __half2* __restrict__ y_l,  // [NN*8]
    __half2* __restrict__ agg,        // [NN*8]
    int* __restrict__ deg)            // [NN]
{
    long long gid = (long long)blockIdx.x * 256 + threadIdx.x;
    int e  = (int)(gid >> 3);
    int cp = (int)(gid & 7);
    if (e >= NE) return;

    int s = ei[e];
    int t = ei[NE + e];

    __half2 v = y_l[s * 8 + cp];
    unsafeAtomicAdd(&agg[t * 8 + cp], v);   // global_atomic_pk_add_f16
    if (cp == 0) atomicAdd(&deg[t], 1);
}

// ---------------------------------------------------------------------------
// Kernel 3: out = agg/max(deg,1) + b_l + self ; logp = log_softmax(out).
// 8 lanes per node, 2 classes per lane; shfl_xor reductions at width 8.
// ---------------------------------------------------------------------------
__global__ __launch_bounds__(256) void finalize_kernel(
    const __half2* __restrict__ agg,
    const int* __restrict__ deg,
    const float* __restrict__ b_l,
    float* __restrict__ logp,
    float* __restrict__ outv)   // holds self (f32) on entry, final out on exit
{
    int tid = blockIdx.x * 256 + threadIdx.x;
    int n  = tid >> 3;
    int cp = tid & 7;
    if (n >= NN) return;

    float d = fmaxf((float)deg[n], 1.0f);
    float2 ag = __half22float2(agg[n * 8 + cp]);
    float2 sf = ((const float2*)outv)[n * 8 + cp];

    float v0 = ag.x / d + b_l[2 * cp]     + sf.x;
    float v1 = ag.y / d + b_l[2 * cp + 1] + sf.y;

    float m = fmaxf(v0, v1);
#pragma unroll
    for (int off = 1; off < 8; off <<= 1)
        m = fmaxf(m, __shfl_xor(m, off, 8));
    float es = expf(v0 - m) + expf(v1 - m);
#pragma unroll
    for (int off = 1; off < 8; off <<= 1)
        es += __shfl_xor(es, off, 8);
    float lse = m + logf(es);

    ((float2*)logp)[n * 8 + cp] = make_float2(v0 - lse, v1 - lse);
    ((float2*)outv)[n * 8 + cp] = make_float2(v0, v1);
}

extern "C" void kernel_launch(void* const* d_in, const int* in_sizes, int n_in,
                              void* d_out, int out_size, void* d_ws, size_t ws_size,
                              hipStream_t stream) {
    const float* x   = (const float*)d_in[0];
    const int*   ei  = (const int*)d_in[1];
    const float* W_l = (const float*)d_in[2];
    const float* b_l = (const float*)d_in[3];
    const float* W_r = (const float*)d_in[4];

    float* logp = (float*)d_out;                    // [NN*NC]
    float* outv = (float*)d_out + (size_t)NN * NC;  // [NN*NC], self scratch

    // ws layout: y_l __half2[NN*8] | agg __half2[NN*8] | deg int[NN]
    __half2* y_l = (__half2*)d_ws;
    __half2* agg = y_l + (size_t)NN * 8;
    int*     deg = (int*)(agg + (size_t)NN * 8);

    // zero agg + deg (contiguous 3.6 MB) — ws is re-poisoned before every call
    hipMemsetAsync(agg, 0, (size_t)NN * 8 * sizeof(__half2) + NN * sizeof(int), stream);

    lin_kernel<<<1024, 256, 0, stream>>>(x, W_l, W_r, y_l, outv);

    long long total = (long long)NE * 8;
    int sblocks = (int)((total + 255) / 256);
    scatter_kernel<<<sblocks, 256, 0, stream>>>(ei, y_l, agg, deg);

    finalize_kernel<<<(NN * 8 + 255) / 256, 256, 0, stream>>>(agg, deg, b_l, logp, outv);
}